// Round 3
// baseline (2451.335 us; speedup 1.0000x reference)
//
#include <hip/hip_runtime.h>

// ---------------------------------------------------------------------------
// ScaledDotProductAttention with mask + deterministic JAX-threefry dropout.
// B=8 H=16 S=1024 D=64, fp32. Outputs: [output | attn_weights] concatenated.
// Round 4: occupancy + issue-count pass.
//   - WTh[512][12] (24 KB): PV runs in two k-halves -> 6 blocks/CU (was 3).
//   - Phase 1 d-slice structure: Q uniform float4 (scalarizable), K one
//     float4/lane, scores accumulate straight into sv[4][8] registers
//     (same FP accumulation order as the previous passing version).
//   - Threefry keep-bits and mask bits computed up front (data-independent),
//     overlapping phase-1 load latency.
// ---------------------------------------------------------------------------

constexpr int Bc = 8, Hc = 16, Sc = 1024, Dc = 64;
constexpr int TQ  = 8;     // q-rows per block
constexpr int WTP = 12;    // WTh row stride in floats (48B, conflict-free b128)

typedef float v4f __attribute__((ext_vector_type(4)));

#define TF_ROUND(x0, x1, r) { x0 += x1; x1 = ((x1 << (r)) | (x1 >> (32 - (r)))); x1 ^= x0; }

// Exact JAX threefry2x32 (20 rounds, 5 key injections).
__host__ __device__ __forceinline__ void threefry2x32(unsigned k0, unsigned k1,
                                                      unsigned x0, unsigned x1,
                                                      unsigned& o0, unsigned& o1) {
  const unsigned k2 = k0 ^ k1 ^ 0x1BD11BDAu;
  x0 += k0; x1 += k1;
  TF_ROUND(x0, x1, 13) TF_ROUND(x0, x1, 15) TF_ROUND(x0, x1, 26) TF_ROUND(x0, x1, 6)
  x0 += k1; x1 += k2 + 1u;
  TF_ROUND(x0, x1, 17) TF_ROUND(x0, x1, 29) TF_ROUND(x0, x1, 16) TF_ROUND(x0, x1, 24)
  x0 += k2; x1 += k0 + 2u;
  TF_ROUND(x0, x1, 13) TF_ROUND(x0, x1, 15) TF_ROUND(x0, x1, 26) TF_ROUND(x0, x1, 6)
  x0 += k0; x1 += k1 + 3u;
  TF_ROUND(x0, x1, 17) TF_ROUND(x0, x1, 29) TF_ROUND(x0, x1, 16) TF_ROUND(x0, x1, 24)
  x0 += k1; x1 += k2 + 4u;
  TF_ROUND(x0, x1, 13) TF_ROUND(x0, x1, 15) TF_ROUND(x0, x1, 26) TF_ROUND(x0, x1, 6)
  x0 += k2; x1 += k0 + 5u;
  o0 = x0; o1 = x1;
}

__global__ __launch_bounds__(256, 6)
void attn_fused(const float* __restrict__ Qg, const float* __restrict__ Kg,
                const float* __restrict__ Vg, const int* __restrict__ Mg,
                float* __restrict__ Og, float* __restrict__ Ag,
                unsigned key0, unsigned key1)
{
  // WTh[k'][q]: half-range transposed weight buffer (k' = k - half*512).
  // 48B rows -> consecutive-k' b128 reads are 2-way (free) bank aliased.
  __shared__ __align__(16) float WTh[512][WTP];   // 24 KB
  __shared__ float REDm[4][8];                    // cross-wave max scratch
  __shared__ float REDs[4][8];                    // cross-wave sum scratch

  const int tid = threadIdx.x;
  const int w   = tid >> 6;          // wave 0..3
  const int l   = tid & 63;          // lane
  const int kl  = w * 64 + l;        // this thread's k offset within 256-group
  const int h   = blockIdx.y;
  const int b   = blockIdx.z;
  const int q0  = blockIdx.x * TQ;
  const size_t bh = (size_t)b * Hc + h;

  const float* __restrict__ Kb = Kg + bh * Sc * Dc;
  const float* __restrict__ Vb = Vg + bh * Sc * Dc;
  const float* __restrict__ Qb = Qg + bh * Sc * Dc + (size_t)q0 * Dc;

  // ---- dropout keep bits (index-only; overlaps everything below) ----
  // bits[i] = o0^o1 of threefry2x32(key, (0, i)); keep if u(bits) < 0.9
  unsigned keep = 0u;
  const unsigned ibase = ((unsigned)((b * Hc + h) * Sc + q0)) * (unsigned)Sc
                         + (unsigned)kl;
  #pragma unroll 8
  for (int t2 = 0; t2 < 32; ++t2) {            // bit t2 = kb*8 + q
    const int kb = t2 >> 3, q = t2 & 7;
    unsigned o0, o1;
    threefry2x32(key0, key1, 0u, ibase + (unsigned)(q * Sc + kb * 256), o0, o1);
    const unsigned bits = o0 ^ o1;
    const float u = __uint_as_float((bits >> 9) | 0x3f800000u) - 1.0f;  // [0,1)
    keep |= (u < 0.9f) ? (1u << t2) : 0u;
  }

  // ---- mask bits (also index-only w.r.t. scores) ----
  unsigned mbits = 0u;
  {
    const int* __restrict__ mc = Mg + (size_t)b * Sc * Sc + (size_t)q0 * Sc + kl;
    #pragma unroll
    for (int kb = 0; kb < 4; ++kb)
      #pragma unroll
      for (int q = 0; q < 8; ++q)
        mbits |= (mc[(size_t)q * Sc + kb * 256] != 0) ? (1u << (kb * 8 + q)) : 0u;
  }

  // ---------------- phase 1: scores = (Q.K)/8, straight to registers ------
  float sv[4][8];
  #pragma unroll
  for (int kb = 0; kb < 4; ++kb)
    #pragma unroll
    for (int q = 0; q < 8; ++q) sv[kb][q] = 0.f;

  #pragma unroll 1
  for (int ds = 0; ds < 16; ++ds) {            // d-slice of 4 floats
    float4 qv[8];
    #pragma unroll
    for (int q = 0; q < 8; ++q)
      qv[q] = *(const float4*)(Qb + (size_t)q * Dc + ds * 4);   // uniform
    #pragma unroll
    for (int kb = 0; kb < 4; ++kb) {
      const float4 kv = *(const float4*)(Kb + (size_t)(kb * 256 + kl) * Dc + ds * 4);
      #pragma unroll
      for (int q = 0; q < 8; ++q) {
        sv[kb][q] = fmaf(kv.x, qv[q].x, sv[kb][q]);
        sv[kb][q] = fmaf(kv.y, qv[q].y, sv[kb][q]);
        sv[kb][q] = fmaf(kv.z, qv[q].z, sv[kb][q]);
        sv[kb][q] = fmaf(kv.w, qv[q].w, sv[kb][q]);
      }
    }
  }

  // ---------------- phase 2: mask, softmax, dropout ----------------
  const float NEG = -__builtin_inff();
  #pragma unroll
  for (int kb = 0; kb < 4; ++kb)
    #pragma unroll
    for (int q = 0; q < 8; ++q) {
      const float s = sv[kb][q] * 0.125f;      // /sqrt(64), exact pow2
      sv[kb][q] = ((mbits >> (kb * 8 + q)) & 1u) ? s : NEG;
    }

  // row max: in-thread over kb, wave shfl, cross-wave via LDS
  float mx[8];
  #pragma unroll
  for (int q = 0; q < 8; ++q) {
    float m = fmaxf(fmaxf(sv[0][q], sv[1][q]), fmaxf(sv[2][q], sv[3][q]));
    #pragma unroll
    for (int off = 32; off > 0; off >>= 1) m = fmaxf(m, __shfl_xor(m, off));
    if (l == 0) REDm[w][q] = m;
  }
  __syncthreads();
  #pragma unroll
  for (int q = 0; q < 8; ++q)
    mx[q] = fmaxf(fmaxf(REDm[0][q], REDm[1][q]), fmaxf(REDm[2][q], REDm[3][q]));

  // exp + row sum
  #pragma unroll
  for (int kb = 0; kb < 4; ++kb)
    #pragma unroll
    for (int q = 0; q < 8; ++q)
      sv[kb][q] = __expf(sv[kb][q] - mx[q]);   // masked -> exp(-inf)=0
  #pragma unroll
  for (int q = 0; q < 8; ++q) {
    float s = (sv[0][q] + sv[1][q]) + (sv[2][q] + sv[3][q]);
    #pragma unroll
    for (int off = 32; off > 0; off >>= 1) s += __shfl_xor(s, off);
    if (l == 0) REDs[w][q] = s;
  }
  __syncthreads();
  float inv9[8];
  #pragma unroll
  for (int q = 0; q < 8; ++q)
    inv9[q] = 1.0f / (((REDs[0][q] + REDs[1][q]) + (REDs[2][q] + REDs[3][q])) * 0.9f);

  // apply dropout + normalize in place; stream attn_weights to global
  float* __restrict__ Arow = Ag + bh * (size_t)Sc * Sc + (size_t)q0 * Sc + kl;
  #pragma unroll
  for (int kb = 0; kb < 4; ++kb)
    #pragma unroll
    for (int q = 0; q < 8; ++q) {
      const float wv = ((keep >> (kb * 8 + q)) & 1u) ? sv[kb][q] * inv9[q] : 0.f;
      sv[kb][q] = wv;
      __builtin_nontemporal_store(wv, &Arow[(size_t)q * Sc + kb * 256]);
    }

  // ---------------- phase 3: output = W . V, two k-halves ----------------
  // thread: ks = tid&15 (k'-slice), dq = tid>>4 (d-quad).
  // Per k: 2 conflict-free b128 WTh reads feed 32 FMAs; V float4 from L2.
  const int ks = tid & 15;
  const int dq = tid >> 4;           // 0..15
  float4 acc[8];
  #pragma unroll
  for (int q = 0; q < 8; ++q) acc[q] = make_float4(0.f, 0.f, 0.f, 0.f);

  #pragma unroll 1
  for (int half = 0; half < 2; ++half) {
    if (half) __syncthreads();       // all reads of previous half done
    #pragma unroll
    for (int kk = 0; kk < 2; ++kk) {
      const int kb = half * 2 + kk;
      const int kr = kk * 256 + kl;  // row within half-buffer
      *(float4*)&WTh[kr][0] = make_float4(sv[kb][0], sv[kb][1], sv[kb][2], sv[kb][3]);
      *(float4*)&WTh[kr][4] = make_float4(sv[kb][4], sv[kb][5], sv[kb][6], sv[kb][7]);
    }
    __syncthreads();                 // half-buffer complete

    #pragma unroll 4
    for (int i = 0; i < 32; ++i) {
      const int kr = i * 16 + ks;
      const int k  = half * 512 + kr;
      const float4 vv = *(const float4*)(Vb + (size_t)k * Dc + dq * 4);
      const float4 lo = *(const float4*)&WTh[kr][0];
      const float4 hi = *(const float4*)&WTh[kr][4];
#define ACCQ(qi, wq) { acc[qi].x = fmaf(wq, vv.x, acc[qi].x); \
                       acc[qi].y = fmaf(wq, vv.y, acc[qi].y); \
                       acc[qi].z = fmaf(wq, vv.z, acc[qi].z); \
                       acc[qi].w = fmaf(wq, vv.w, acc[qi].w); }
      ACCQ(0, lo.x) ACCQ(1, lo.y) ACCQ(2, lo.z) ACCQ(3, lo.w)
      ACCQ(4, hi.x) ACCQ(5, hi.y) ACCQ(6, hi.z) ACCQ(7, hi.w)
#undef ACCQ
    }
  }

  // reduce over the 16 k-slices (lane bits 0..3); dq groups unaffected
  #pragma unroll
  for (int off = 1; off <= 8; off <<= 1) {
    #pragma unroll
    for (int q = 0; q < 8; ++q) {
      acc[q].x += __shfl_xor(acc[q].x, off);
      acc[q].y += __shfl_xor(acc[q].y, off);
      acc[q].z += __shfl_xor(acc[q].z, off);
      acc[q].w += __shfl_xor(acc[q].w, off);
    }
  }
  if ((l & 15) == 0) {
    float* __restrict__ Obase = Og + bh * (size_t)Sc * Dc + (size_t)q0 * Dc + dq * 4;
    #pragma unroll
    for (int q = 0; q < 8; ++q) {
      const v4f t = { acc[q].x, acc[q].y, acc[q].z, acc[q].w };
      __builtin_nontemporal_store(t, (v4f*)(Obase + (size_t)q * Dc));
    }
  }
}

extern "C" void kernel_launch(void* const* d_in, const int* in_sizes, int n_in,
                              void* d_out, int out_size, void* d_ws, size_t ws_size,
                              hipStream_t stream) {
  const float* Qg = (const float*)d_in[0];
  const float* Kg = (const float*)d_in[1];
  const float* Vg = (const float*)d_in[2];
  const int*   Mg = (const int*)d_in[3];
  float* Og = (float*)d_out;
  float* Ag = Og + (size_t)Bc * Hc * Sc * Dc;   // attn_weights after output

  // drop_key = fold_in(key(42), 7) = threefry2x32(key=[0,42], counts=[0,7])
  unsigned k0, k1;
  threefry2x32(0u, 42u, 0u, 7u, k0, k1);

  dim3 grid(Sc / TQ, Hc, Bc);   // (128, 16, 8)
  attn_fused<<<grid, 256, 0, stream>>>(Qg, Kg, Vg, Mg, Og, Ag, k0, k1);
}

// Round 4
// 2092.892 us; speedup vs baseline: 1.1713x; 1.1713x over previous
//
#include <hip/hip_runtime.h>

// ---------------------------------------------------------------------------
// ScaledDotProductAttention with mask + deterministic JAX-threefry dropout.
// B=8 H=16 S=1024 D=64, fp32. Outputs: [output | attn_weights] concatenated.
// Round 5: fix R4's register-spill catastrophe (launch_bounds(256,6) -> VGPR=40
// with ~80 live regs => scratch traffic, WRITE_SIZE 4.5x). Now:
//   - __launch_bounds__(256, 4): 128-VGPR budget, no spills, 4 blocks/CU.
//   - XCD-aware bijective swizzle: each XCD owns one batch b; q-blocks sweep
//     fastest within (b,h) -> K/V working set ~1MB per XCD L2, mask slice 4MB.
//   - Phase 1 d-slice: Q uniform float4 (SGPR-scalarized), K float4/lane,
//     scores straight into sv[4][8] registers (same FP order as passing runs).
//   - Phase 3: two k-halves through WTh[512][12] (24 KB), conflict-free b128.
// ---------------------------------------------------------------------------

constexpr int Bc = 8, Hc = 16, Sc = 1024, Dc = 64;
constexpr int TQ  = 8;     // q-rows per block
constexpr int WTP = 12;    // WTh row stride in floats (48B, conflict-free b128)

typedef float v4f __attribute__((ext_vector_type(4)));

#define TF_ROUND(x0, x1, r) { x0 += x1; x1 = ((x1 << (r)) | (x1 >> (32 - (r)))); x1 ^= x0; }

// Exact JAX threefry2x32 (20 rounds, 5 key injections).
__host__ __device__ __forceinline__ void threefry2x32(unsigned k0, unsigned k1,
                                                      unsigned x0, unsigned x1,
                                                      unsigned& o0, unsigned& o1) {
  const unsigned k2 = k0 ^ k1 ^ 0x1BD11BDAu;
  x0 += k0; x1 += k1;
  TF_ROUND(x0, x1, 13) TF_ROUND(x0, x1, 15) TF_ROUND(x0, x1, 26) TF_ROUND(x0, x1, 6)
  x0 += k1; x1 += k2 + 1u;
  TF_ROUND(x0, x1, 17) TF_ROUND(x0, x1, 29) TF_ROUND(x0, x1, 16) TF_ROUND(x0, x1, 24)
  x0 += k2; x1 += k0 + 2u;
  TF_ROUND(x0, x1, 13) TF_ROUND(x0, x1, 15) TF_ROUND(x0, x1, 26) TF_ROUND(x0, x1, 6)
  x0 += k0; x1 += k1 + 3u;
  TF_ROUND(x0, x1, 17) TF_ROUND(x0, x1, 29) TF_ROUND(x0, x1, 16) TF_ROUND(x0, x1, 24)
  x0 += k1; x1 += k2 + 4u;
  TF_ROUND(x0, x1, 13) TF_ROUND(x0, x1, 15) TF_ROUND(x0, x1, 26) TF_ROUND(x0, x1, 6)
  x0 += k2; x1 += k0 + 5u;
  o0 = x0; o1 = x1;
}

__global__ __launch_bounds__(256, 4)
void attn_fused(const float* __restrict__ Qg, const float* __restrict__ Kg,
                const float* __restrict__ Vg, const int* __restrict__ Mg,
                float* __restrict__ Og, float* __restrict__ Ag,
                unsigned key0, unsigned key1)
{
  // WTh[k'][q]: half-range transposed weight buffer (k' = k - half*512).
  // 48B rows -> consecutive-k' b128 reads are 2-way (free) bank aliased.
  __shared__ __align__(16) float WTh[512][WTP];   // 24 KB
  __shared__ float REDm[4][8];                    // cross-wave max scratch
  __shared__ float REDs[4][8];                    // cross-wave sum scratch

  // ---- XCD-aware bijective swizzle (nwg=16384, 8 XCDs, round-robin HW map).
  // XCD x executes wg in [x*2048,(x+1)*2048) = exactly batch b=x; q-blocks
  // sweep fastest within (b,h) -> K/V stays hot in the XCD-private L2.
  const unsigned orig = blockIdx.x;
  const unsigned wg   = (orig & 7u) * 2048u + (orig >> 3);
  const int q0 = (int)(wg & 127u) * TQ;
  const int h  = (int)(wg >> 7) & 15;
  const int b  = (int)(wg >> 11);

  const int tid = threadIdx.x;
  const int w   = tid >> 6;          // wave 0..3
  const int l   = tid & 63;          // lane
  const int kl  = w * 64 + l;        // this thread's k offset within 256-group
  const size_t bh = (size_t)b * Hc + h;

  const float* __restrict__ Kb = Kg + bh * Sc * Dc;
  const float* __restrict__ Vb = Vg + bh * Sc * Dc;
  const float* __restrict__ Qb = Qg + bh * Sc * Dc + (size_t)q0 * Dc;

  // ---- dropout keep bits (index-only; overlaps everything below) ----
  // bits[i] = o0^o1 of threefry2x32(key, (0, i)); keep if u(bits) < 0.9
  unsigned keep = 0u;
  const unsigned ibase = ((unsigned)((b * Hc + h) * Sc + q0)) * (unsigned)Sc
                         + (unsigned)kl;
  #pragma unroll 8
  for (int t2 = 0; t2 < 32; ++t2) {            // bit t2 = kb*8 + q
    const int kb = t2 >> 3, q = t2 & 7;
    unsigned o0, o1;
    threefry2x32(key0, key1, 0u, ibase + (unsigned)(q * Sc + kb * 256), o0, o1);
    const unsigned bits = o0 ^ o1;
    const float u = __uint_as_float((bits >> 9) | 0x3f800000u) - 1.0f;  // [0,1)
    keep |= (u < 0.9f) ? (1u << t2) : 0u;
  }

  // ---- mask bits (also index-only w.r.t. scores) ----
  unsigned mbits = 0u;
  {
    const int* __restrict__ mc = Mg + (size_t)b * Sc * Sc + (size_t)q0 * Sc + kl;
    #pragma unroll
    for (int kb = 0; kb < 4; ++kb)
      #pragma unroll
      for (int q = 0; q < 8; ++q)
        mbits |= (mc[(size_t)q * Sc + kb * 256] != 0) ? (1u << (kb * 8 + q)) : 0u;
  }

  // ---------------- phase 1: scores = (Q.K)/8, straight to registers ------
  float sv[4][8];
  #pragma unroll
  for (int kb = 0; kb < 4; ++kb)
    #pragma unroll
    for (int q = 0; q < 8; ++q) sv[kb][q] = 0.f;

  #pragma unroll 1
  for (int ds = 0; ds < 16; ++ds) {            // d-slice of 4 floats
    float4 qv[8];
    #pragma unroll
    for (int q = 0; q < 8; ++q)
      qv[q] = *(const float4*)(Qb + (size_t)q * Dc + ds * 4);   // uniform -> SGPR
    #pragma unroll
    for (int kb = 0; kb < 4; ++kb) {
      const float4 kv = *(const float4*)(Kb + (size_t)(kb * 256 + kl) * Dc + ds * 4);
      #pragma unroll
      for (int q = 0; q < 8; ++q) {
        sv[kb][q] = fmaf(kv.x, qv[q].x, sv[kb][q]);
        sv[kb][q] = fmaf(kv.y, qv[q].y, sv[kb][q]);
        sv[kb][q] = fmaf(kv.z, qv[q].z, sv[kb][q]);
        sv[kb][q] = fmaf(kv.w, qv[q].w, sv[kb][q]);
      }
    }
  }

  // ---------------- phase 2: mask, softmax, dropout ----------------
  const float NEG = -__builtin_inff();
  #pragma unroll
  for (int kb = 0; kb < 4; ++kb)
    #pragma unroll
    for (int q = 0; q < 8; ++q) {
      const float s = sv[kb][q] * 0.125f;      // /sqrt(64), exact pow2
      sv[kb][q] = ((mbits >> (kb * 8 + q)) & 1u) ? s : NEG;
    }

  // row max: in-thread over kb, wave shfl, cross-wave via LDS
  float mx[8];
  #pragma unroll
  for (int q = 0; q < 8; ++q) {
    float m = fmaxf(fmaxf(sv[0][q], sv[1][q]), fmaxf(sv[2][q], sv[3][q]));
    #pragma unroll
    for (int off = 32; off > 0; off >>= 1) m = fmaxf(m, __shfl_xor(m, off));
    if (l == 0) REDm[w][q] = m;
  }
  __syncthreads();
  #pragma unroll
  for (int q = 0; q < 8; ++q)
    mx[q] = fmaxf(fmaxf(REDm[0][q], REDm[1][q]), fmaxf(REDm[2][q], REDm[3][q]));

  // exp + row sum
  #pragma unroll
  for (int kb = 0; kb < 4; ++kb)
    #pragma unroll
    for (int q = 0; q < 8; ++q)
      sv[kb][q] = __expf(sv[kb][q] - mx[q]);   // masked -> exp(-inf)=0
  #pragma unroll
  for (int q = 0; q < 8; ++q) {
    float s = (sv[0][q] + sv[1][q]) + (sv[2][q] + sv[3][q]);
    #pragma unroll
    for (int off = 32; off > 0; off >>= 1) s += __shfl_xor(s, off);
    if (l == 0) REDs[w][q] = s;
  }
  __syncthreads();
  float inv9[8];
  #pragma unroll
  for (int q = 0; q < 8; ++q)
    inv9[q] = 1.0f / (((REDs[0][q] + REDs[1][q]) + (REDs[2][q] + REDs[3][q])) * 0.9f);

  // apply dropout + normalize in place; stream attn_weights to global
  float* __restrict__ Arow = Ag + bh * (size_t)Sc * Sc + (size_t)q0 * Sc + kl;
  #pragma unroll
  for (int kb = 0; kb < 4; ++kb)
    #pragma unroll
    for (int q = 0; q < 8; ++q) {
      const float wv = ((keep >> (kb * 8 + q)) & 1u) ? sv[kb][q] * inv9[q] : 0.f;
      sv[kb][q] = wv;
      __builtin_nontemporal_store(wv, &Arow[(size_t)q * Sc + kb * 256]);
    }

  // ---------------- phase 3: output = W . V, two k-halves ----------------
  // thread: ks = tid&15 (k'-slice), dq = tid>>4 (d-quad).
  // Per k: 2 conflict-free b128 WTh reads feed 32 FMAs; V float4 from L2.
  const int ks = tid & 15;
  const int dq = tid >> 4;           // 0..15
  float4 acc[8];
  #pragma unroll
  for (int q = 0; q < 8; ++q) acc[q] = make_float4(0.f, 0.f, 0.f, 0.f);

  #pragma unroll 1
  for (int half = 0; half < 2; ++half) {
    if (half) __syncthreads();       // all reads of previous half done
    #pragma unroll
    for (int kk = 0; kk < 2; ++kk) {
      const int kb = half * 2 + kk;
      const int kr = kk * 256 + kl;  // row within half-buffer
      *(float4*)&WTh[kr][0] = make_float4(sv[kb][0], sv[kb][1], sv[kb][2], sv[kb][3]);
      *(float4*)&WTh[kr][4] = make_float4(sv[kb][4], sv[kb][5], sv[kb][6], sv[kb][7]);
    }
    __syncthreads();                 // half-buffer complete

    #pragma unroll 4
    for (int i = 0; i < 32; ++i) {
      const int kr = i * 16 + ks;
      const int k  = half * 512 + kr;
      const float4 vv = *(const float4*)(Vb + (size_t)k * Dc + dq * 4);
      const float4 lo = *(const float4*)&WTh[kr][0];
      const float4 hi = *(const float4*)&WTh[kr][4];
#define ACCQ(qi, wq) { acc[qi].x = fmaf(wq, vv.x, acc[qi].x); \
                       acc[qi].y = fmaf(wq, vv.y, acc[qi].y); \
                       acc[qi].z = fmaf(wq, vv.z, acc[qi].z); \
                       acc[qi].w = fmaf(wq, vv.w, acc[qi].w); }
      ACCQ(0, lo.x) ACCQ(1, lo.y) ACCQ(2, lo.z) ACCQ(3, lo.w)
      ACCQ(4, hi.x) ACCQ(5, hi.y) ACCQ(6, hi.z) ACCQ(7, hi.w)
#undef ACCQ
    }
  }

  // reduce over the 16 k-slices (lane bits 0..3); dq groups unaffected
  #pragma unroll
  for (int off = 1; off <= 8; off <<= 1) {
    #pragma unroll
    for (int q = 0; q < 8; ++q) {
      acc[q].x += __shfl_xor(acc[q].x, off);
      acc[q].y += __shfl_xor(acc[q].y, off);
      acc[q].z += __shfl_xor(acc[q].z, off);
      acc[q].w += __shfl_xor(acc[q].w, off);
    }
  }
  if ((l & 15) == 0) {
    float* __restrict__ Obase = Og + bh * (size_t)Sc * Dc + (size_t)q0 * Dc + dq * 4;
    #pragma unroll
    for (int q = 0; q < 8; ++q) {
      const v4f t = { acc[q].x, acc[q].y, acc[q].z, acc[q].w };
      __builtin_nontemporal_store(t, (v4f*)(Obase + (size_t)q * Dc));
    }
  }
}

extern "C" void kernel_launch(void* const* d_in, const int* in_sizes, int n_in,
                              void* d_out, int out_size, void* d_ws, size_t ws_size,
                              hipStream_t stream) {
  const float* Qg = (const float*)d_in[0];
  const float* Kg = (const float*)d_in[1];
  const float* Vg = (const float*)d_in[2];
  const int*   Mg = (const int*)d_in[3];
  float* Og = (float*)d_out;
  float* Ag = Og + (size_t)Bc * Hc * Sc * Dc;   // attn_weights after output

  // drop_key = fold_in(key(42), 7) = threefry2x32(key=[0,42], counts=[0,7])
  unsigned k0, k1;
  threefry2x32(0u, 42u, 0u, 7u, k0, k1);

  attn_fused<<<dim3(16384), 256, 0, stream>>>(Qg, Kg, Vg, Mg, Og, Ag, k0, k1);
}

// Round 5
// 1883.662 us; speedup vs baseline: 1.3014x; 1.1111x over previous
//
#include <hip/hip_runtime.h>

// ---------------------------------------------------------------------------
// ScaledDotProductAttention with mask + deterministic JAX-threefry dropout.
// B=8 H=16 S=1024 D=64, fp32. Outputs: [output | attn_weights] concatenated.
// Round 6: kill the scratch demotion. R4/R3 indexed sv[kb][q] with a RUNTIME
// 'half' loop variable -> whole sv array demoted to scratch (rule #20):
// 1.7GB excess HBM writes. PV halves are now hand-unrolled so every sv index
// is compile-time; sv lives in VGPRs end-to-end.
//   - __launch_bounds__(256, 4): 128-VGPR budget, 4 blocks/CU.
//   - XCD-aware bijective swizzle: each XCD owns one batch b.
//   - Phase 1 d-slice: Q uniform float4, K float4/lane, scores straight into
//     sv[4][8] registers (same FP accumulation order as passing runs).
//   - Phase 3: two k-halves through WTh[512][12] (24 KB), conflict-free b128.
// ---------------------------------------------------------------------------

constexpr int Bc = 8, Hc = 16, Sc = 1024, Dc = 64;
constexpr int TQ  = 8;     // q-rows per block
constexpr int WTP = 12;    // WTh row stride in floats (48B, conflict-free b128)

typedef float v4f __attribute__((ext_vector_type(4)));

#define TF_ROUND(x0, x1, r) { x0 += x1; x1 = ((x1 << (r)) | (x1 >> (32 - (r)))); x1 ^= x0; }

// Exact JAX threefry2x32 (20 rounds, 5 key injections).
__host__ __device__ __forceinline__ void threefry2x32(unsigned k0, unsigned k1,
                                                      unsigned x0, unsigned x1,
                                                      unsigned& o0, unsigned& o1) {
  const unsigned k2 = k0 ^ k1 ^ 0x1BD11BDAu;
  x0 += k0; x1 += k1;
  TF_ROUND(x0, x1, 13) TF_ROUND(x0, x1, 15) TF_ROUND(x0, x1, 26) TF_ROUND(x0, x1, 6)
  x0 += k1; x1 += k2 + 1u;
  TF_ROUND(x0, x1, 17) TF_ROUND(x0, x1, 29) TF_ROUND(x0, x1, 16) TF_ROUND(x0, x1, 24)
  x0 += k2; x1 += k0 + 2u;
  TF_ROUND(x0, x1, 13) TF_ROUND(x0, x1, 15) TF_ROUND(x0, x1, 26) TF_ROUND(x0, x1, 6)
  x0 += k0; x1 += k1 + 3u;
  TF_ROUND(x0, x1, 17) TF_ROUND(x0, x1, 29) TF_ROUND(x0, x1, 16) TF_ROUND(x0, x1, 24)
  x0 += k1; x1 += k2 + 4u;
  TF_ROUND(x0, x1, 13) TF_ROUND(x0, x1, 15) TF_ROUND(x0, x1, 26) TF_ROUND(x0, x1, 6)
  x0 += k2; x1 += k0 + 5u;
  o0 = x0; o1 = x1;
}

__global__ __launch_bounds__(256, 4)
void attn_fused(const float* __restrict__ Qg, const float* __restrict__ Kg,
                const float* __restrict__ Vg, const int* __restrict__ Mg,
                float* __restrict__ Og, float* __restrict__ Ag,
                unsigned key0, unsigned key1)
{
  // WTh[k'][q]: half-range transposed weight buffer (k' = k - half*512).
  // 48B rows -> consecutive-k' b128 reads are 2-way (free) bank aliased.
  __shared__ __align__(16) float WTh[512][WTP];   // 24 KB
  __shared__ float REDm[4][8];                    // cross-wave max scratch
  __shared__ float REDs[4][8];                    // cross-wave sum scratch

  // ---- XCD-aware bijective swizzle (nwg=16384, 8 XCDs, round-robin HW map).
  // XCD x executes wg in [x*2048,(x+1)*2048) = exactly batch b=x; q-blocks
  // sweep fastest within (b,h) -> K/V stays hot in the XCD-private L2.
  const unsigned orig = blockIdx.x;
  const unsigned wg   = (orig & 7u) * 2048u + (orig >> 3);
  const int q0 = (int)(wg & 127u) * TQ;
  const int h  = (int)(wg >> 7) & 15;
  const int b  = (int)(wg >> 11);

  const int tid = threadIdx.x;
  const int w   = tid >> 6;          // wave 0..3
  const int l   = tid & 63;          // lane
  const int kl  = w * 64 + l;        // this thread's k offset within 256-group
  const size_t bh = (size_t)b * Hc + h;

  const float* __restrict__ Kb = Kg + bh * Sc * Dc;
  const float* __restrict__ Vb = Vg + bh * Sc * Dc;
  const float* __restrict__ Qb = Qg + bh * Sc * Dc + (size_t)q0 * Dc;

  // ---- mask bits first (loads issue early; latency hides under threefry) --
  unsigned mbits = 0u;
  {
    const int* __restrict__ mc = Mg + (size_t)b * Sc * Sc + (size_t)q0 * Sc + kl;
    #pragma unroll
    for (int kb = 0; kb < 4; ++kb)
      #pragma unroll
      for (int q = 0; q < 8; ++q)
        mbits |= (mc[(size_t)q * Sc + kb * 256] != 0) ? (1u << (kb * 8 + q)) : 0u;
  }

  // ---- dropout keep bits (pure ALU, index-only) ----
  // bits[i] = o0^o1 of threefry2x32(key, (0, i)); keep if u(bits) < 0.9
  unsigned keep = 0u;
  const unsigned ibase = ((unsigned)((b * Hc + h) * Sc + q0)) * (unsigned)Sc
                         + (unsigned)kl;
  #pragma unroll 8
  for (int t2 = 0; t2 < 32; ++t2) {            // bit t2 = kb*8 + q
    const int kb = t2 >> 3, q = t2 & 7;
    unsigned o0, o1;
    threefry2x32(key0, key1, 0u, ibase + (unsigned)(q * Sc + kb * 256), o0, o1);
    const unsigned bits = o0 ^ o1;
    const float u = __uint_as_float((bits >> 9) | 0x3f800000u) - 1.0f;  // [0,1)
    keep |= (u < 0.9f) ? (1u << t2) : 0u;
  }

  // ---------------- phase 1: scores = (Q.K)/8, straight to registers ------
  float sv[4][8];
  #pragma unroll
  for (int kb = 0; kb < 4; ++kb)
    #pragma unroll
    for (int q = 0; q < 8; ++q) sv[kb][q] = 0.f;

  #pragma unroll 1
  for (int ds = 0; ds < 16; ++ds) {            // d-slice of 4 floats
    float4 qv[8];
    #pragma unroll
    for (int q = 0; q < 8; ++q)
      qv[q] = *(const float4*)(Qb + (size_t)q * Dc + ds * 4);   // uniform
    #pragma unroll
    for (int kb = 0; kb < 4; ++kb) {
      const float4 kv = *(const float4*)(Kb + (size_t)(kb * 256 + kl) * Dc + ds * 4);
      #pragma unroll
      for (int q = 0; q < 8; ++q) {
        sv[kb][q] = fmaf(kv.x, qv[q].x, sv[kb][q]);
        sv[kb][q] = fmaf(kv.y, qv[q].y, sv[kb][q]);
        sv[kb][q] = fmaf(kv.z, qv[q].z, sv[kb][q]);
        sv[kb][q] = fmaf(kv.w, qv[q].w, sv[kb][q]);
      }
    }
  }

  // ---------------- phase 2: mask, softmax, dropout ----------------
  const float NEG = -__builtin_inff();
  #pragma unroll
  for (int kb = 0; kb < 4; ++kb)
    #pragma unroll
    for (int q = 0; q < 8; ++q) {
      const float s = sv[kb][q] * 0.125f;      // /sqrt(64), exact pow2
      sv[kb][q] = ((mbits >> (kb * 8 + q)) & 1u) ? s : NEG;
    }

  // row max: in-thread over kb, wave shfl, cross-wave via LDS
  float mx[8];
  #pragma unroll
  for (int q = 0; q < 8; ++q) {
    float m = fmaxf(fmaxf(sv[0][q], sv[1][q]), fmaxf(sv[2][q], sv[3][q]));
    #pragma unroll
    for (int off = 32; off > 0; off >>= 1) m = fmaxf(m, __shfl_xor(m, off));
    if (l == 0) REDm[w][q] = m;
  }
  __syncthreads();
  #pragma unroll
  for (int q = 0; q < 8; ++q)
    mx[q] = fmaxf(fmaxf(REDm[0][q], REDm[1][q]), fmaxf(REDm[2][q], REDm[3][q]));

  // exp + row sum
  #pragma unroll
  for (int kb = 0; kb < 4; ++kb)
    #pragma unroll
    for (int q = 0; q < 8; ++q)
      sv[kb][q] = __expf(sv[kb][q] - mx[q]);   // masked -> exp(-inf)=0
  #pragma unroll
  for (int q = 0; q < 8; ++q) {
    float s = (sv[0][q] + sv[1][q]) + (sv[2][q] + sv[3][q]);
    #pragma unroll
    for (int off = 32; off > 0; off >>= 1) s += __shfl_xor(s, off);
    if (l == 0) REDs[w][q] = s;
  }
  __syncthreads();
  float inv9[8];
  #pragma unroll
  for (int q = 0; q < 8; ++q)
    inv9[q] = 1.0f / (((REDs[0][q] + REDs[1][q]) + (REDs[2][q] + REDs[3][q])) * 0.9f);

  // apply dropout + normalize in place; stream attn_weights to global
  float* __restrict__ Arow = Ag + bh * (size_t)Sc * Sc + (size_t)q0 * Sc + kl;
  #pragma unroll
  for (int kb = 0; kb < 4; ++kb)
    #pragma unroll
    for (int q = 0; q < 8; ++q) {
      const float wv = ((keep >> (kb * 8 + q)) & 1u) ? sv[kb][q] * inv9[q] : 0.f;
      sv[kb][q] = wv;
      __builtin_nontemporal_store(wv, &Arow[(size_t)q * Sc + kb * 256]);
    }

  // ---------------- phase 3: output = W . V, two k-halves ----------------
  // Hand-unrolled halves: every sv index below is a compile-time constant,
  // so sv stays in VGPRs (no scratch). thread: ks = tid&15 (k'-slice),
  // dq = tid>>4 (d-quad). Per k: 2 conflict-free b128 WTh reads -> 32 FMAs.
  const int ks = tid & 15;
  const int dq = tid >> 4;           // 0..15
  float4 acc[8];
  #pragma unroll
  for (int q = 0; q < 8; ++q) acc[q] = make_float4(0.f, 0.f, 0.f, 0.f);

#define ACCQ(qi, wq) { acc[qi].x = fmaf(wq, vv.x, acc[qi].x); \
                       acc[qi].y = fmaf(wq, vv.y, acc[qi].y); \
                       acc[qi].z = fmaf(wq, vv.z, acc[qi].z); \
                       acc[qi].w = fmaf(wq, vv.w, acc[qi].w); }
#define PV_COMPUTE(halfc)                                                    \
    _Pragma("unroll 4")                                                      \
    for (int i = 0; i < 32; ++i) {                                           \
      const int kr = i * 16 + ks;                                            \
      const float4 vv = *(const float4*)(Vb + (size_t)((halfc) * 512 + kr) * Dc + dq * 4); \
      const float4 lo = *(const float4*)&WTh[kr][0];                         \
      const float4 hi = *(const float4*)&WTh[kr][4];                         \
      ACCQ(0, lo.x) ACCQ(1, lo.y) ACCQ(2, lo.z) ACCQ(3, lo.w)                \
      ACCQ(4, hi.x) ACCQ(5, hi.y) ACCQ(6, hi.z) ACCQ(7, hi.w)                \
    }

  // ---- half 0: kb = 0,1 ----
  *(float4*)&WTh[kl][0]       = make_float4(sv[0][0], sv[0][1], sv[0][2], sv[0][3]);
  *(float4*)&WTh[kl][4]       = make_float4(sv[0][4], sv[0][5], sv[0][6], sv[0][7]);
  *(float4*)&WTh[256 + kl][0] = make_float4(sv[1][0], sv[1][1], sv[1][2], sv[1][3]);
  *(float4*)&WTh[256 + kl][4] = make_float4(sv[1][4], sv[1][5], sv[1][6], sv[1][7]);
  __syncthreads();                 // half-buffer complete
  PV_COMPUTE(0)

  __syncthreads();                 // all reads of half 0 done
  // ---- half 1: kb = 2,3 ----
  *(float4*)&WTh[kl][0]       = make_float4(sv[2][0], sv[2][1], sv[2][2], sv[2][3]);
  *(float4*)&WTh[kl][4]       = make_float4(sv[2][4], sv[2][5], sv[2][6], sv[2][7]);
  *(float4*)&WTh[256 + kl][0] = make_float4(sv[3][0], sv[3][1], sv[3][2], sv[3][3]);
  *(float4*)&WTh[256 + kl][4] = make_float4(sv[3][4], sv[3][5], sv[3][6], sv[3][7]);
  __syncthreads();                 // half-buffer complete
  PV_COMPUTE(1)

#undef PV_COMPUTE
#undef ACCQ

  // reduce over the 16 k-slices (lane bits 0..3); dq groups unaffected
  #pragma unroll
  for (int off = 1; off <= 8; off <<= 1) {
    #pragma unroll
    for (int q = 0; q < 8; ++q) {
      acc[q].x += __shfl_xor(acc[q].x, off);
      acc[q].y += __shfl_xor(acc[q].y, off);
      acc[q].z += __shfl_xor(acc[q].z, off);
      acc[q].w += __shfl_xor(acc[q].w, off);
    }
  }
  if ((l & 15) == 0) {
    float* __restrict__ Obase = Og + bh * (size_t)Sc * Dc + (size_t)q0 * Dc + dq * 4;
    #pragma unroll
    for (int q = 0; q < 8; ++q) {
      const v4f t = { acc[q].x, acc[q].y, acc[q].z, acc[q].w };
      __builtin_nontemporal_store(t, (v4f*)(Obase + (size_t)q * Dc));
    }
  }
}

extern "C" void kernel_launch(void* const* d_in, const int* in_sizes, int n_in,
                              void* d_out, int out_size, void* d_ws, size_t ws_size,
                              hipStream_t stream) {
  const float* Qg = (const float*)d_in[0];
  const float* Kg = (const float*)d_in[1];
  const float* Vg = (const float*)d_in[2];
  const int*   Mg = (const int*)d_in[3];
  float* Og = (float*)d_out;
  float* Ag = Og + (size_t)Bc * Hc * Sc * Dc;   // attn_weights after output

  // drop_key = fold_in(key(42), 7) = threefry2x32(key=[0,42], counts=[0,7])
  unsigned k0, k1;
  threefry2x32(0u, 42u, 0u, 7u, k0, k1);

  attn_fused<<<dim3(16384), 256, 0, stream>>>(Qg, Kg, Vg, Mg, Og, Ag, k0, k1);
}